// Round 7
// baseline (208.504 us; speedup 1.0000x reference)
//
#include <hip/hip_runtime.h>
#include <hip/hip_bf16.h>

typedef unsigned short u16;
typedef __bf16 bf16x8 __attribute__((ext_vector_type(8)));
typedef __bf16 bf16x4 __attribute__((ext_vector_type(4)));
typedef float f32x4 __attribute__((ext_vector_type(4)));
typedef unsigned short u16x8 __attribute__((ext_vector_type(8)));

// round-to-nearest-even fp32 -> bf16 (epilogue paths only)
__device__ inline u16 f2bf(float f) {
    union { float f; unsigned u; } v; v.f = f;
    unsigned r = v.u + 0x7fffu + ((v.u >> 16) & 1u);
    return (u16)(r >> 16);
}

// ---------------------------------------------------------------------------
// Convert x and 4 weights to bf16, contiguous in ws:
//   [x_bf 4194304][wq 1048576][wk][wv][wo]
// ---------------------------------------------------------------------------
__global__ void convert_kernel(const float* __restrict__ x,
                               const float* __restrict__ wq, const float* __restrict__ wk,
                               const float* __restrict__ wv, const float* __restrict__ wo,
                               u16* __restrict__ dst) {
    long g = (long)blockIdx.x * blockDim.x + threadIdx.x;  // group of 4 elements
    const float* src; long base;
    const long GX = 1048576, GW = 262144;  // groups: x = 4.19M els, each w = 1.05M els
    if (g < GX)            { src = x;  base = 0; }
    else if (g < GX + GW)  { src = wq; base = GX; }
    else if (g < GX + 2*GW){ src = wk; base = GX + GW; }
    else if (g < GX + 3*GW){ src = wv; base = GX + 2*GW; }
    else                   { src = wo; base = GX + 3*GW; }
    long rel = g - base;
    float4 v = reinterpret_cast<const float4*>(src)[rel];
    ushort4 o;
    o.x = f2bf(v.x); o.y = f2bf(v.y); o.z = f2bf(v.z); o.w = f2bf(v.w);
    reinterpret_cast<ushort4*>(dst)[g] = o;
}

// ---------------------------------------------------------------------------
// QKV projection, fused z = 0:q, 1:k, 2:v (selected from swizzled block id).
//   q_ws/k_ws: [bh][s][64] bf16 (q pre-scaled by log2(e)/8: folds the softmax
//              1/sqrt(64) AND the exp->exp2 conversion)
//   v_ws:      [bh][64][s] bf16 (transposed so attention PV B-frags are contiguous)
//
// 512-thread 8-wave DOUBLE-BUFFERED single-barrier schedule (R6).
// R7: XCD-locality swizzle (T1). Default dispatch round-robins consecutive
// blocks across the 8 XCDs, so blocks sharing a W-tile / A-tile get no L2
// reuse (staging is ~384 MB through L3). Remap so XCD x owns 3 W-tiles
// (L2-resident, 256 KB each) and sweeps t0; all XCDs stream the same A-tile
// concurrently (one L3 fetch). Bijection on grid 768 = 8 XCD * 96.
// ---------------------------------------------------------------------------
__global__ void __launch_bounds__(512)
qkv_gemm(const u16* __restrict__ x_bf,
         const u16* __restrict__ wq, const u16* __restrict__ wk, const u16* __restrict__ wv,
         const float* __restrict__ sq, const float* __restrict__ sk, const float* __restrict__ sv,
         const float* __restrict__ bq, const float* __restrict__ bk, const float* __restrict__ bv,
         u16* __restrict__ q_ws, u16* __restrict__ k_ws, u16* __restrict__ v_ws) {
    __shared__ __align__(16) u16 As[2][128 * 64];
    __shared__ __align__(16) u16 Bs[2][128 * 64];

    // XCD swizzle: f%8 = XCD (HW round-robin); XCD owns W-tiles wsel=x*3+j/32,
    // sweeps t0=j%32. Bijective: (x,j) <-> (wsel,t0).
    const int f   = blockIdx.x + 32 * (blockIdx.y + 8 * blockIdx.z);
    const int xcd = f & 7, j = f >> 3;
    const int wsel = xcd * 3 + (j >> 5);     // 0..23 = (n0-tile, z)
    const int t0 = (j & 31) * 128;
    const int z  = wsel >> 3;
    const int n0 = (wsel & 7) * 128;

    const u16* W   = (z == 0) ? wq : (z == 1) ? wk : wv;
    const float* sp = (z == 0) ? sq : (z == 1) ? sk : sv;
    const float* bp = (z == 0) ? bq : (z == 1) ? bk : bv;
    u16* dst = (z == 0) ? q_ws : (z == 1) ? k_ws : v_ws;
    // q gets 1/8 (softmax scale) * log2(e) (so attn can use exp2 natively)
    const float extra = (z == 0) ? 0.125f * 1.44269504088896f : 1.0f;

    const int tid = threadIdx.x;
    const int wid = tid >> 6, lane = tid & 63, quad = lane >> 4, ln = lane & 15;
    const int wm = wid >> 2, wn = wid & 3;   // 2x4 wave grid, wave tile 64x32

    // wave-uniform staging assignment: waves 0-3 -> A chunks, 4-7 -> B chunks
    const bool stA = (wid < 4);
    const u16* gbase = stA ? x_bf : W;
    const int r0 = stA ? t0 : n0;
    const int cbase = (wid & 3) * 4;         // 4 chunks of 1 KB per wave

    f32x4 acc[4][2];
#pragma unroll
    for (int im = 0; im < 4; im++)
#pragma unroll
        for (int in = 0; in < 2; in++) acc[im][in] = (f32x4){0.f, 0.f, 0.f, 0.f};

    // per-lane staging source geometry (swizzled global source, linear LDS)
    const int sb   = cbase * 1024 + lane * 16;
    const int srow = sb >> 7;
    const int scb  = (sb & 127) ^ ((srow & 7) << 4);

#define Q_STAGE(buf, k0)                                                              \
    {                                                                                 \
        const u16* g = gbase + (long)(r0 + srow) * 1024 + (k0) + (scb >> 1);          \
        u16* d = (stA ? &As[buf][0] : &Bs[buf][0]) + cbase * 512;                     \
        _Pragma("unroll")                                                             \
        for (int i = 0; i < 4; i++) {                                                 \
            __builtin_amdgcn_global_load_lds(                                         \
                (const __attribute__((address_space(1))) void*)(g + (long)i * 8 * 1024), \
                (__attribute__((address_space(3))) void*)(d + i * 512), 16, 0, 0);    \
        }                                                                             \
    }

    Q_STAGE(0, 0);
    __syncthreads();

    int cur = 0;
    for (int k0 = 0; k0 < 1024; k0 += 64) {
        if (k0 + 64 < 1024) Q_STAGE(cur ^ 1, k0 + 64);
        const char* Ac = (const char*)&As[cur][0];
        const char* Bc = (const char*)&Bs[cur][0];
#pragma unroll
        for (int ks = 0; ks < 2; ks++) {
            bf16x8 af[4], bfr[2];
#pragma unroll
            for (int im = 0; im < 4; im++) {
                int r = wm * 64 + im * 16 + ln;
                int byt = (r * 128 + ks * 64 + quad * 16) ^ ((r & 7) << 4);
                af[im] = *reinterpret_cast<const bf16x8*>(Ac + byt);
            }
#pragma unroll
            for (int in = 0; in < 2; in++) {
                int r = wn * 32 + in * 16 + ln;
                int byt = (r * 128 + ks * 64 + quad * 16) ^ ((r & 7) << 4);
                bfr[in] = *reinterpret_cast<const bf16x8*>(Bc + byt);
            }
#pragma unroll
            for (int im = 0; im < 4; im++)
#pragma unroll
                for (int in = 0; in < 2; in++)
                    acc[im][in] = __builtin_amdgcn_mfma_f32_16x16x32_bf16(af[im], bfr[in], acc[im][in], 0, 0, 0);
        }
        // single barrier: (a) protects buf[cur] reuse, (b) drains DMA into buf^1
        __syncthreads();
        cur ^= 1;
    }
#undef Q_STAGE

    const float s = sp[0] * extra;
#pragma unroll
    for (int in = 0; in < 2; in++) {
        int col = n0 + wn * 32 + in * 16 + ln;
        float bias = bp[col] * extra;
        int h = col >> 6, d = col & 63;
#pragma unroll
        for (int im = 0; im < 4; im++) {
            int rbase = t0 + wm * 64 + im * 16 + quad * 4;
#pragma unroll
            for (int j2 = 0; j2 < 4; j2++) {
                int t = rbase + j2;
                int b = t >> 11, ss = t & 2047;
                int bh = b * 16 + h;
                float val = acc[im][in][j2] * s + bias;
                long idx = (z < 2) ? ((long)(bh * 2048 + ss) * 64 + d)
                                   : ((long)(bh * 64 + d) * 2048 + ss);
                dst[idx] = f2bf(val);
            }
        }
    }
}

// ---------------------------------------------------------------------------
// Attention: per (q-tile of 128, bh). 512 threads = 8 waves, each wave owns
// 16 q-rows.
//
// R7: XCD swizzle — XCD x owns bh = x*4 + j/16 (4 bh * 512 KB K/V = 2 MB,
// L2-resident) and sweeps q0 = j%16. Previously the 16 q-blocks of one bh
// were scattered round-robin over all 8 XCDs (K/V re-fetched from L3;
// FETCH_SIZE 69.7 MB). Bijective on grid 512 = 8 * 64.
//
// Schedule: K/V staged by global_load_lds into DOUBLE-BUFFERED swizzled-
// linear LDS; one barrier per K-tile; denominator on the MFMA pipe
// (acc_l = mfma(ap, ONES, acc_l)); swapped QK^T (S^T = mfma(K, Q)).
// ---------------------------------------------------------------------------
#define LDP 72

__global__ void __launch_bounds__(512)
attn_kernel(const u16* __restrict__ q_ws, const u16* __restrict__ k_ws,
            const u16* __restrict__ v_ws, u16* __restrict__ ctx) {
    __shared__ __align__(16) u16 Kb[2][4096];   // [buf][64 keys][64 d] swizzled
    __shared__ __align__(16) u16 Vb[2][4096];   // [buf][64 d][64 keys] swizzled
    __shared__ u16 Pt[128 * LDP];               // [q][key] exp(scores) bf16 (padded)

    const int tid = threadIdx.x;
    const int wid = tid >> 6, lane = tid & 63, quad = lane >> 4, ln = lane & 15;

    // XCD swizzle: XCD x pins 4 bh's K/V in its L2, sweeps q-tiles
    const int f   = blockIdx.x + 16 * blockIdx.y;
    const int xcd = f & 7, j = f >> 3;
    const int bh  = xcd * 4 + (j >> 4);
    const int q0  = (j & 15) * 128;

    const u16* qbase = q_ws + (long)bh * 2048 * 64;
    const u16* kbase = k_ws + (long)bh * 2048 * 64;
    const u16* vbase = v_ws + (long)bh * 64 * 2048;

    // staging geometry: wave w fills LDS bytes [w*1024 + lane*16)
    const int srow = wid * 8 + (lane >> 3);                  // tile row 0..63
    const int sel  = 8 * ((lane & 7) ^ ((lane >> 3) & 7));   // swizzled src col (els)
    // fragment-read XOR term (row ^= pattern depends only on ln&7)
    const int xr = (ln & 7) << 4;

    // Q fragments held in registers for the whole K loop
    bf16x8 aq[2];
#pragma unroll
    for (int ks = 0; ks < 2; ks++)
        aq[ks] = *reinterpret_cast<const bf16x8*>(
            qbase + (long)(q0 + wid * 16 + ln) * 64 + ks * 32 + quad * 8);

    // all-ones bf16 B-fragment for the denominator MFMA
    bf16x8 vones;
#pragma unroll
    for (int i = 0; i < 8; i++) vones[i] = (__bf16)1.0f;

    f32x4 acc_o[4];
    f32x4 acc_l = (f32x4){0.f, 0.f, 0.f, 0.f};
#pragma unroll
    for (int dt = 0; dt < 4; dt++) acc_o[dt] = (f32x4){0.f, 0.f, 0.f, 0.f};

    // incremental DMA source pointers (avoids per-iter 64-bit addr rebuild)
    const u16* kp = kbase + (long)srow * 64 + sel;     // advances by 64*64 els/tile
    const u16* vp = vbase + (long)srow * 2048 + sel;   // advances by 64 els/tile

    // prologue: stage tile 0 into buf 0
    __builtin_amdgcn_global_load_lds((const __attribute__((address_space(1))) void*)kp,
                                     (__attribute__((address_space(3))) void*)(&Kb[0][wid * 512]),
                                     16, 0, 0);
    __builtin_amdgcn_global_load_lds((const __attribute__((address_space(1))) void*)vp,
                                     (__attribute__((address_space(3))) void*)(&Vb[0][wid * 512]),
                                     16, 0, 0);
    kp += 4096; vp += 64;
    __syncthreads();

    int cur = 0;
    for (int kt = 0; kt < 2048; kt += 64) {
        // issue next tile's DMA first; it flies under this tile's compute
        if (kt + 64 < 2048) {
            __builtin_amdgcn_global_load_lds((const __attribute__((address_space(1))) void*)kp,
                                             (__attribute__((address_space(3))) void*)(&Kb[cur ^ 1][wid * 512]),
                                             16, 0, 0);
            __builtin_amdgcn_global_load_lds((const __attribute__((address_space(1))) void*)vp,
                                             (__attribute__((address_space(3))) void*)(&Vb[cur ^ 1][wid * 512]),
                                             16, 0, 0);
            kp += 4096; vp += 64;
        }
        const char* Kc = (const char*)(&Kb[cur][0]);
        const char* Vc = (const char*)(&Vb[cur][0]);

        // S^T = K Q^T (swapped). Lane (quad,ln): q = ln, keys = k8*16+quad*4+j
#pragma unroll
        for (int k8 = 0; k8 < 4; k8++) {
            bf16x8 a0 = *reinterpret_cast<const bf16x8*>(
                Kc + (k8 * 16 + ln) * 128 + ((quad * 16) ^ xr));
            bf16x8 a1 = *reinterpret_cast<const bf16x8*>(
                Kc + (k8 * 16 + ln) * 128 + ((64 + quad * 16) ^ xr));
            f32x4 t = (f32x4){0.f, 0.f, 0.f, 0.f};
            __builtin_amdgcn_s_setprio(1);
            t = __builtin_amdgcn_mfma_f32_16x16x32_bf16(a0, aq[0], t, 0, 0, 0);
            t = __builtin_amdgcn_mfma_f32_16x16x32_bf16(a1, aq[1], t, 0, 0, 0);
            __builtin_amdgcn_s_setprio(0);
            // bare v_exp_f32 (log2e folded into q); compiler-path bf16 casts
            __bf16 p0 = (__bf16)__builtin_amdgcn_exp2f(t[0]);
            __bf16 p1 = (__bf16)__builtin_amdgcn_exp2f(t[1]);
            __bf16 p2 = (__bf16)__builtin_amdgcn_exp2f(t[2]);
            __bf16 p3 = (__bf16)__builtin_amdgcn_exp2f(t[3]);
            *reinterpret_cast<bf16x4*>(Pt + (wid * 16 + ln) * LDP + k8 * 16 + quad * 4)
                = (bf16x4){p0, p1, p2, p3};
        }

        // O += P V ; l += P 1  (A-frag reads of Pt are wave-local rows)
#pragma unroll
        for (int step = 0; step < 2; step++) {
            bf16x8 ap = *reinterpret_cast<const bf16x8*>(
                Pt + (wid * 16 + ln) * LDP + step * 32 + quad * 8);
            bf16x8 bv0 = *reinterpret_cast<const bf16x8*>(
                Vc + (0 * 16 + ln) * 128 + ((step * 64 + quad * 16) ^ xr));
            bf16x8 bv1 = *reinterpret_cast<const bf16x8*>(
                Vc + (1 * 16 + ln) * 128 + ((step * 64 + quad * 16) ^ xr));
            bf16x8 bv2 = *reinterpret_cast<const bf16x8*>(
                Vc + (2 * 16 + ln) * 128 + ((step * 64 + quad * 16) ^ xr));
            bf16x8 bv3 = *reinterpret_cast<const bf16x8*>(
                Vc + (3 * 16 + ln) * 128 + ((step * 64 + quad * 16) ^ xr));
            __builtin_amdgcn_s_setprio(1);
            acc_o[0] = __builtin_amdgcn_mfma_f32_16x16x32_bf16(ap, bv0, acc_o[0], 0, 0, 0);
            acc_o[1] = __builtin_amdgcn_mfma_f32_16x16x32_bf16(ap, bv1, acc_o[1], 0, 0, 0);
            acc_o[2] = __builtin_amdgcn_mfma_f32_16x16x32_bf16(ap, bv2, acc_o[2], 0, 0, 0);
            acc_o[3] = __builtin_amdgcn_mfma_f32_16x16x32_bf16(ap, bv3, acc_o[3], 0, 0, 0);
            acc_l    = __builtin_amdgcn_mfma_f32_16x16x32_bf16(ap, vones, acc_l, 0, 0, 0);
            __builtin_amdgcn_s_setprio(0);
        }
        // single barrier per K-tile: orders (a) all reads of buf[cur] before it
        // is overwritten next iter, (b) drains this iter's DMA into buf[cur^1]
        __syncthreads();
        cur ^= 1;
    }

    // write ctx [t][h*64+d] bf16; acc_l[j] is the denominator for q-row
    // wid*16 + quad*4 + j (same row acc_o[dt][j] holds) — no shuffle needed
    const int b = bh >> 4, h = bh & 15;
#pragma unroll
    for (int j2 = 0; j2 < 4; j2++) {
        float rinv = 1.0f / acc_l[j2];
        int t = b * 2048 + q0 + wid * 16 + quad * 4 + j2;
#pragma unroll
        for (int dt = 0; dt < 4; dt++) {
            float val = acc_o[dt][j2] * rinv;
            ctx[(long)t * 1024 + h * 64 + dt * 16 + ln] = f2bf(val);
        }
    }
}

// ---------------------------------------------------------------------------
// Output projection: d_out[t][o] = ctx @ wo^T * s_o + b_o  (fp32 out)
// 512-thread 8-wave double-buffered single-barrier (R5).
// R7: XCD swizzle — XCD x owns n0 = x (W-column L2-resident), sweeps t0.
// Bijective on grid 256 = 8 * 32.
// ---------------------------------------------------------------------------
__global__ void __launch_bounds__(512)
o_gemm(const u16* __restrict__ ctx, const u16* __restrict__ wo,
       const float* __restrict__ so, const float* __restrict__ bo,
       float* __restrict__ out) {
    __shared__ __align__(16) u16 As[2][128 * 64];
    __shared__ __align__(16) u16 Bs[2][128 * 64];
    const int tid = threadIdx.x;
    const int wid = tid >> 6, lane = tid & 63, quad = lane >> 4, ln = lane & 15;
    const int wm = wid >> 2, wn = wid & 3;   // 2x4 wave grid, wave tile 64x32

    const int f   = blockIdx.x + 32 * blockIdx.y;
    const int xcd = f & 7, j = f >> 3;
    const int t0 = j * 128, n0 = xcd * 128;

    // wave-uniform staging assignment: waves 0-3 -> A chunks, 4-7 -> B chunks
    const bool stA = (wid < 4);
    const u16* gbase = stA ? ctx : wo;
    const int r0 = stA ? t0 : n0;
    const int cbase = (wid & 3) * 4;         // 4 chunks of 1 KB per wave

    f32x4 acc[4][2];
#pragma unroll
    for (int im = 0; im < 4; im++)
#pragma unroll
        for (int in = 0; in < 2; in++) acc[im][in] = (f32x4){0.f, 0.f, 0.f, 0.f};

    // per-lane staging source geometry (swizzled global source, linear LDS)
    const int sb   = cbase * 1024 + lane * 16;
    const int srow = sb >> 7;
    const int scb  = (sb & 127) ^ ((srow & 7) << 4);

#define O_STAGE(buf, k0)                                                              \
    {                                                                                 \
        const u16* g = gbase + (long)(r0 + srow) * 1024 + (k0) + (scb >> 1);          \
        u16* d = (stA ? &As[buf][0] : &Bs[buf][0]) + cbase * 512;                     \
        _Pragma("unroll")                                                             \
        for (int i = 0; i < 4; i++) {                                                 \
            __builtin_amdgcn_global_load_lds(                                         \
                (const __attribute__((address_space(1))) void*)(g + (long)i * 8 * 1024), \
                (__attribute__((address_space(3))) void*)(d + i * 512), 16, 0, 0);    \
        }                                                                             \
    }

    O_STAGE(0, 0);
    __syncthreads();

    int cur = 0;
    for (int k0 = 0; k0 < 1024; k0 += 64) {
        if (k0 + 64 < 1024) O_STAGE(cur ^ 1, k0 + 64);
        const char* Ac = (const char*)&As[cur][0];
        const char* Bc = (const char*)&Bs[cur][0];
#pragma unroll
        for (int ks = 0; ks < 2; ks++) {
            bf16x8 af[4], bfr[2];
#pragma unroll
            for (int im = 0; im < 4; im++) {
                int r = wm * 64 + im * 16 + ln;
                int byt = (r * 128 + ks * 64 + quad * 16) ^ ((r & 7) << 4);
                af[im] = *reinterpret_cast<const bf16x8*>(Ac + byt);
            }
#pragma unroll
            for (int in = 0; in < 2; in++) {
                int r = wn * 32 + in * 16 + ln;
                int byt = (r * 128 + ks * 64 + quad * 16) ^ ((r & 7) << 4);
                bfr[in] = *reinterpret_cast<const bf16x8*>(Bc + byt);
            }
#pragma unroll
            for (int im = 0; im < 4; im++)
#pragma unroll
                for (int in = 0; in < 2; in++)
                    acc[im][in] = __builtin_amdgcn_mfma_f32_16x16x32_bf16(af[im], bfr[in], acc[im][in], 0, 0, 0);
        }
        // single barrier: (a) protects buf[cur] reuse, (b) drains DMA into buf^1
        __syncthreads();
        cur ^= 1;
    }
#undef O_STAGE

    const float s = so[0];
#pragma unroll
    for (int in = 0; in < 2; in++) {
        int col = n0 + wn * 32 + in * 16 + ln;
        float bias = bo[col];
#pragma unroll
        for (int im = 0; im < 4; im++) {
            int rbase = t0 + wm * 64 + im * 16 + quad * 4;
#pragma unroll
            for (int j2 = 0; j2 < 4; j2++)
                out[(long)(rbase + j2) * 1024 + col] = acc[im][in][j2] * s + bias;
        }
    }
}

// ---------------------------------------------------------------------------
extern "C" void kernel_launch(void* const* d_in, const int* in_sizes, int n_in,
                              void* d_out, int out_size, void* d_ws, size_t ws_size,
                              hipStream_t stream) {
    const float* x   = (const float*)d_in[0];
    const float* w_q = (const float*)d_in[1];
    const float* s_q = (const float*)d_in[2];
    const float* b_q = (const float*)d_in[3];
    const float* w_k = (const float*)d_in[4];
    const float* s_k = (const float*)d_in[5];
    const float* b_k = (const float*)d_in[6];
    const float* w_v = (const float*)d_in[7];
    const float* s_v = (const float*)d_in[8];
    const float* b_v = (const float*)d_in[9];
    const float* w_o = (const float*)d_in[10];
    const float* s_o = (const float*)d_in[11];
    const float* b_o = (const float*)d_in[12];

    if (ws_size < (size_t)50331648) return;  // need 48 MB of scratch

    u16* ws     = (u16*)d_ws;
    u16* x_bf   = ws;                    // 4096*1024
    u16* wq_bf  = x_bf  + 4194304;       // 1024*1024 each
    u16* wk_bf  = wq_bf + 1048576;
    u16* wv_bf  = wk_bf + 1048576;
    u16* wo_bf  = wv_bf + 1048576;
    u16* q_ws   = wo_bf + 1048576;       // [32 bh][2048 s][64 d]
    u16* k_ws   = q_ws  + 4194304;
    u16* v_ws   = k_ws  + 4194304;       // [32 bh][64 d][2048 s]
    u16* ctx_ws = v_ws  + 4194304;       // [4096 t][1024]

    convert_kernel<<<dim3(8192), dim3(256), 0, stream>>>(x, w_q, w_k, w_v, w_o, ws);
    qkv_gemm<<<dim3(32, 8, 3), dim3(512), 0, stream>>>(x_bf, wq_bf, wk_bf, wv_bf,
                                                       s_q, s_k, s_v, b_q, b_k, b_v,
                                                       q_ws, k_ws, v_ws);
    attn_kernel<<<dim3(16, 32), dim3(512), 0, stream>>>(q_ws, k_ws, v_ws, ctx_ws);
    o_gemm<<<dim3(32, 8), dim3(512), 0, stream>>>(ctx_ws, wo_bf, s_o, b_o, (float*)d_out);
}

// Round 8
// 188.037 us; speedup vs baseline: 1.1088x; 1.1088x over previous
//
#include <hip/hip_runtime.h>
#include <hip/hip_bf16.h>

typedef unsigned short u16;
typedef __bf16 bf16x8 __attribute__((ext_vector_type(8)));
typedef __bf16 bf16x4 __attribute__((ext_vector_type(4)));
typedef float f32x4 __attribute__((ext_vector_type(4)));
typedef unsigned short u16x8 __attribute__((ext_vector_type(8)));

// round-to-nearest-even fp32 -> bf16 (epilogue paths only)
__device__ inline u16 f2bf(float f) {
    union { float f; unsigned u; } v; v.f = f;
    unsigned r = v.u + 0x7fffu + ((v.u >> 16) & 1u);
    return (u16)(r >> 16);
}

// ---------------------------------------------------------------------------
// Convert x and 4 weights to bf16, contiguous in ws:
//   [x_bf 4194304][wq 1048576][wk][wv][wo]
// ---------------------------------------------------------------------------
__global__ void convert_kernel(const float* __restrict__ x,
                               const float* __restrict__ wq, const float* __restrict__ wk,
                               const float* __restrict__ wv, const float* __restrict__ wo,
                               u16* __restrict__ dst) {
    long g = (long)blockIdx.x * blockDim.x + threadIdx.x;  // group of 4 elements
    const float* src; long base;
    const long GX = 1048576, GW = 262144;  // groups: x = 4.19M els, each w = 1.05M els
    if (g < GX)            { src = x;  base = 0; }
    else if (g < GX + GW)  { src = wq; base = GX; }
    else if (g < GX + 2*GW){ src = wk; base = GX + GW; }
    else if (g < GX + 3*GW){ src = wv; base = GX + 2*GW; }
    else                   { src = wo; base = GX + 3*GW; }
    long rel = g - base;
    float4 v = reinterpret_cast<const float4*>(src)[rel];
    ushort4 o;
    o.x = f2bf(v.x); o.y = f2bf(v.y); o.z = f2bf(v.z); o.w = f2bf(v.w);
    reinterpret_cast<ushort4*>(dst)[g] = o;
}

// ---------------------------------------------------------------------------
// QKV projection. z = 0:q, 1:k, 2:v. (R6 natural-order grid RESTORED.)
// NOTE (R7 lesson): with t0-major blockIdx and HW round-robin block->XCD,
// each XCD already owns A-tiles t0 = x mod 8 (1 MB, L2-pinned, 8x reuse)
// while W streams shared. The R7 W-pinning swizzle destroyed A-reuse and
// regressed ~22 us. Do NOT re-swizzle this kernel.
//
// 512-thread 8-wave DOUBLE-BUFFERED single-barrier schedule: waves 0-3 stage
// A chunks, 4-7 stage B chunks into buf^1 BEFORE computing buf; one
// __syncthreads per K-step. Swizzle: linear LDS dest, pre-swizzled global
// source, XOR'd fragment reads (byte ^= (row&7)<<4 involution).
// ---------------------------------------------------------------------------
__global__ void __launch_bounds__(512)
qkv_gemm(const u16* __restrict__ x_bf,
         const u16* __restrict__ wq, const u16* __restrict__ wk, const u16* __restrict__ wv,
         const float* __restrict__ sq, const float* __restrict__ sk, const float* __restrict__ sv,
         const float* __restrict__ bq, const float* __restrict__ bk, const float* __restrict__ bv,
         u16* __restrict__ q_ws, u16* __restrict__ k_ws, u16* __restrict__ v_ws) {
    __shared__ __align__(16) u16 As[2][128 * 64];
    __shared__ __align__(16) u16 Bs[2][128 * 64];
    const int z = blockIdx.z;
    const u16* W   = (z == 0) ? wq : (z == 1) ? wk : wv;
    const float* sp = (z == 0) ? sq : (z == 1) ? sk : sv;
    const float* bp = (z == 0) ? bq : (z == 1) ? bk : bv;
    u16* dst = (z == 0) ? q_ws : (z == 1) ? k_ws : v_ws;
    // q gets 1/8 (softmax scale) * log2(e) (so attn can use exp2 natively)
    const float extra = (z == 0) ? 0.125f * 1.44269504088896f : 1.0f;
    const int t0 = blockIdx.x * 128, n0 = blockIdx.y * 128;

    const int tid = threadIdx.x;
    const int wid = tid >> 6, lane = tid & 63, quad = lane >> 4, ln = lane & 15;
    const int wm = wid >> 2, wn = wid & 3;   // 2x4 wave grid, wave tile 64x32

    // wave-uniform staging assignment: waves 0-3 -> A chunks, 4-7 -> B chunks
    const bool stA = (wid < 4);
    const u16* gbase = stA ? x_bf : W;
    const int r0 = stA ? t0 : n0;
    const int cbase = (wid & 3) * 4;         // 4 chunks of 1 KB per wave

    f32x4 acc[4][2];
#pragma unroll
    for (int im = 0; im < 4; im++)
#pragma unroll
        for (int in = 0; in < 2; in++) acc[im][in] = (f32x4){0.f, 0.f, 0.f, 0.f};

    // per-lane staging source geometry (swizzled global source, linear LDS)
    const int sb   = cbase * 1024 + lane * 16;
    const int srow = sb >> 7;
    const int scb  = (sb & 127) ^ ((srow & 7) << 4);

#define Q_STAGE(buf, k0)                                                              \
    {                                                                                 \
        const u16* g = gbase + (long)(r0 + srow) * 1024 + (k0) + (scb >> 1);          \
        u16* d = (stA ? &As[buf][0] : &Bs[buf][0]) + cbase * 512;                     \
        _Pragma("unroll")                                                             \
        for (int i = 0; i < 4; i++) {                                                 \
            __builtin_amdgcn_global_load_lds(                                         \
                (const __attribute__((address_space(1))) void*)(g + (long)i * 8 * 1024), \
                (__attribute__((address_space(3))) void*)(d + i * 512), 16, 0, 0);    \
        }                                                                             \
    }

    Q_STAGE(0, 0);
    __syncthreads();

    int cur = 0;
    for (int k0 = 0; k0 < 1024; k0 += 64) {
        if (k0 + 64 < 1024) Q_STAGE(cur ^ 1, k0 + 64);
        const char* Ac = (const char*)&As[cur][0];
        const char* Bc = (const char*)&Bs[cur][0];
#pragma unroll
        for (int ks = 0; ks < 2; ks++) {
            bf16x8 af[4], bfr[2];
#pragma unroll
            for (int im = 0; im < 4; im++) {
                int r = wm * 64 + im * 16 + ln;
                int byt = (r * 128 + ks * 64 + quad * 16) ^ ((r & 7) << 4);
                af[im] = *reinterpret_cast<const bf16x8*>(Ac + byt);
            }
#pragma unroll
            for (int in = 0; in < 2; in++) {
                int r = wn * 32 + in * 16 + ln;
                int byt = (r * 128 + ks * 64 + quad * 16) ^ ((r & 7) << 4);
                bfr[in] = *reinterpret_cast<const bf16x8*>(Bc + byt);
            }
#pragma unroll
            for (int im = 0; im < 4; im++)
#pragma unroll
                for (int in = 0; in < 2; in++)
                    acc[im][in] = __builtin_amdgcn_mfma_f32_16x16x32_bf16(af[im], bfr[in], acc[im][in], 0, 0, 0);
        }
        // single barrier: (a) protects buf[cur] reuse, (b) drains DMA into buf^1
        __syncthreads();
        cur ^= 1;
    }
#undef Q_STAGE

    const float s = sp[0] * extra;
#pragma unroll
    for (int in = 0; in < 2; in++) {
        int col = n0 + wn * 32 + in * 16 + ln;
        float bias = bp[col] * extra;
        int h = col >> 6, d = col & 63;
#pragma unroll
        for (int im = 0; im < 4; im++) {
            int rbase = t0 + wm * 64 + im * 16 + quad * 4;
#pragma unroll
            for (int j2 = 0; j2 < 4; j2++) {
                int t = rbase + j2;
                int b = t >> 11, ss = t & 2047;
                int bh = b * 16 + h;
                float val = acc[im][in][j2] * s + bias;
                long idx = (z < 2) ? ((long)(bh * 2048 + ss) * 64 + d)
                                   : ((long)(bh * 64 + d) * 2048 + ss);
                dst[idx] = f2bf(val);
            }
        }
    }
}

// ---------------------------------------------------------------------------
// Attention: per (q-tile of 128, bh). 512 threads = 8 waves, each wave owns
// 16 q-rows. (R7 XCD swizzle KEPT — measured: FETCH 69.7->12.3 MB, -4 us.)
//
// XCD swizzle: XCD x pins 4 bh's K/V (2 MB, L2-resident), sweeps q-tiles.
// Default round-robin gave a 16 MB/XCD K/V working set (thrash).
//
// Schedule: K/V staged by global_load_lds into DOUBLE-BUFFERED swizzled-
// linear LDS; one barrier per K-tile; denominator on the MFMA pipe
// (acc_l = mfma(ap, ONES, acc_l)); swapped QK^T (S^T = mfma(K, Q)).
// ---------------------------------------------------------------------------
#define LDP 72

__global__ void __launch_bounds__(512)
attn_kernel(const u16* __restrict__ q_ws, const u16* __restrict__ k_ws,
            const u16* __restrict__ v_ws, u16* __restrict__ ctx) {
    __shared__ __align__(16) u16 Kb[2][4096];   // [buf][64 keys][64 d] swizzled
    __shared__ __align__(16) u16 Vb[2][4096];   // [buf][64 d][64 keys] swizzled
    __shared__ u16 Pt[128 * LDP];               // [q][key] exp(scores) bf16 (padded)

    const int tid = threadIdx.x;
    const int wid = tid >> 6, lane = tid & 63, quad = lane >> 4, ln = lane & 15;

    // XCD swizzle: XCD x pins 4 bh's K/V in its L2, sweeps q-tiles
    const int f   = blockIdx.x + 16 * blockIdx.y;
    const int xcd = f & 7, j = f >> 3;
    const int bh  = xcd * 4 + (j >> 4);
    const int q0  = (j & 15) * 128;

    const u16* qbase = q_ws + (long)bh * 2048 * 64;
    const u16* kbase = k_ws + (long)bh * 2048 * 64;
    const u16* vbase = v_ws + (long)bh * 64 * 2048;

    // staging geometry: wave w fills LDS bytes [w*1024 + lane*16)
    const int srow = wid * 8 + (lane >> 3);                  // tile row 0..63
    const int sel  = 8 * ((lane & 7) ^ ((lane >> 3) & 7));   // swizzled src col (els)
    // fragment-read XOR term (row ^= pattern depends only on ln&7)
    const int xr = (ln & 7) << 4;

    // Q fragments held in registers for the whole K loop
    bf16x8 aq[2];
#pragma unroll
    for (int ks = 0; ks < 2; ks++)
        aq[ks] = *reinterpret_cast<const bf16x8*>(
            qbase + (long)(q0 + wid * 16 + ln) * 64 + ks * 32 + quad * 8);

    // all-ones bf16 B-fragment for the denominator MFMA
    bf16x8 vones;
#pragma unroll
    for (int i = 0; i < 8; i++) vones[i] = (__bf16)1.0f;

    f32x4 acc_o[4];
    f32x4 acc_l = (f32x4){0.f, 0.f, 0.f, 0.f};
#pragma unroll
    for (int dt = 0; dt < 4; dt++) acc_o[dt] = (f32x4){0.f, 0.f, 0.f, 0.f};

    // incremental DMA source pointers (avoids per-iter 64-bit addr rebuild)
    const u16* kp = kbase + (long)srow * 64 + sel;     // advances by 64*64 els/tile
    const u16* vp = vbase + (long)srow * 2048 + sel;   // advances by 64 els/tile

    // prologue: stage tile 0 into buf 0
    __builtin_amdgcn_global_load_lds((const __attribute__((address_space(1))) void*)kp,
                                     (__attribute__((address_space(3))) void*)(&Kb[0][wid * 512]),
                                     16, 0, 0);
    __builtin_amdgcn_global_load_lds((const __attribute__((address_space(1))) void*)vp,
                                     (__attribute__((address_space(3))) void*)(&Vb[0][wid * 512]),
                                     16, 0, 0);
    kp += 4096; vp += 64;
    __syncthreads();

    int cur = 0;
    for (int kt = 0; kt < 2048; kt += 64) {
        // issue next tile's DMA first; it flies under this tile's compute
        if (kt + 64 < 2048) {
            __builtin_amdgcn_global_load_lds((const __attribute__((address_space(1))) void*)kp,
                                             (__attribute__((address_space(3))) void*)(&Kb[cur ^ 1][wid * 512]),
                                             16, 0, 0);
            __builtin_amdgcn_global_load_lds((const __attribute__((address_space(1))) void*)vp,
                                             (__attribute__((address_space(3))) void*)(&Vb[cur ^ 1][wid * 512]),
                                             16, 0, 0);
            kp += 4096; vp += 64;
        }
        const char* Kc = (const char*)(&Kb[cur][0]);
        const char* Vc = (const char*)(&Vb[cur][0]);

        // S^T = K Q^T (swapped). Lane (quad,ln): q = ln, keys = k8*16+quad*4+j
#pragma unroll
        for (int k8 = 0; k8 < 4; k8++) {
            bf16x8 a0 = *reinterpret_cast<const bf16x8*>(
                Kc + (k8 * 16 + ln) * 128 + ((quad * 16) ^ xr));
            bf16x8 a1 = *reinterpret_cast<const bf16x8*>(
                Kc + (k8 * 16 + ln) * 128 + ((64 + quad * 16) ^ xr));
            f32x4 t = (f32x4){0.f, 0.f, 0.f, 0.f};
            __builtin_amdgcn_s_setprio(1);
            t = __builtin_amdgcn_mfma_f32_16x16x32_bf16(a0, aq[0], t, 0, 0, 0);
            t = __builtin_amdgcn_mfma_f32_16x16x32_bf16(a1, aq[1], t, 0, 0, 0);
            __builtin_amdgcn_s_setprio(0);
            // bare v_exp_f32 (log2e folded into q); compiler-path bf16 casts
            __bf16 p0 = (__bf16)__builtin_amdgcn_exp2f(t[0]);
            __bf16 p1 = (__bf16)__builtin_amdgcn_exp2f(t[1]);
            __bf16 p2 = (__bf16)__builtin_amdgcn_exp2f(t[2]);
            __bf16 p3 = (__bf16)__builtin_amdgcn_exp2f(t[3]);
            *reinterpret_cast<bf16x4*>(Pt + (wid * 16 + ln) * LDP + k8 * 16 + quad * 4)
                = (bf16x4){p0, p1, p2, p3};
        }

        // O += P V ; l += P 1  (A-frag reads of Pt are wave-local rows)
#pragma unroll
        for (int step = 0; step < 2; step++) {
            bf16x8 ap = *reinterpret_cast<const bf16x8*>(
                Pt + (wid * 16 + ln) * LDP + step * 32 + quad * 8);
            bf16x8 bv0 = *reinterpret_cast<const bf16x8*>(
                Vc + (0 * 16 + ln) * 128 + ((step * 64 + quad * 16) ^ xr));
            bf16x8 bv1 = *reinterpret_cast<const bf16x8*>(
                Vc + (1 * 16 + ln) * 128 + ((step * 64 + quad * 16) ^ xr));
            bf16x8 bv2 = *reinterpret_cast<const bf16x8*>(
                Vc + (2 * 16 + ln) * 128 + ((step * 64 + quad * 16) ^ xr));
            bf16x8 bv3 = *reinterpret_cast<const bf16x8*>(
                Vc + (3 * 16 + ln) * 128 + ((step * 64 + quad * 16) ^ xr));
            __builtin_amdgcn_s_setprio(1);
            acc_o[0] = __builtin_amdgcn_mfma_f32_16x16x32_bf16(ap, bv0, acc_o[0], 0, 0, 0);
            acc_o[1] = __builtin_amdgcn_mfma_f32_16x16x32_bf16(ap, bv1, acc_o[1], 0, 0, 0);
            acc_o[2] = __builtin_amdgcn_mfma_f32_16x16x32_bf16(ap, bv2, acc_o[2], 0, 0, 0);
            acc_o[3] = __builtin_amdgcn_mfma_f32_16x16x32_bf16(ap, bv3, acc_o[3], 0, 0, 0);
            acc_l    = __builtin_amdgcn_mfma_f32_16x16x32_bf16(ap, vones, acc_l, 0, 0, 0);
            __builtin_amdgcn_s_setprio(0);
        }
        // single barrier per K-tile: orders (a) all reads of buf[cur] before it
        // is overwritten next iter, (b) drains this iter's DMA into buf[cur^1]
        __syncthreads();
        cur ^= 1;
    }

    // write ctx [t][h*64+d] bf16; acc_l[j] is the denominator for q-row
    // wid*16 + quad*4 + j (same row acc_o[dt][j] holds) — no shuffle needed
    const int b = bh >> 4, h = bh & 15;
#pragma unroll
    for (int j2 = 0; j2 < 4; j2++) {
        float rinv = 1.0f / acc_l[j2];
        int t = b * 2048 + q0 + wid * 16 + quad * 4 + j2;
#pragma unroll
        for (int dt = 0; dt < 4; dt++) {
            float val = acc_o[dt][j2] * rinv;
            ctx[(long)t * 1024 + h * 64 + dt * 16 + ln] = f2bf(val);
        }
    }
}

// ---------------------------------------------------------------------------
// Output projection: d_out[t][o] = ctx @ wo^T * s_o + b_o  (fp32 out)
// (R6 natural-order grid RESTORED — same R7 lesson as qkv: default
// round-robin already pins 4 ctx-tiles per XCD with 8x reuse.)
// 512-thread 8-wave double-buffered single-barrier.
// ---------------------------------------------------------------------------
__global__ void __launch_bounds__(512)
o_gemm(const u16* __restrict__ ctx, const u16* __restrict__ wo,
       const float* __restrict__ so, const float* __restrict__ bo,
       float* __restrict__ out) {
    __shared__ __align__(16) u16 As[2][128 * 64];
    __shared__ __align__(16) u16 Bs[2][128 * 64];
    const int tid = threadIdx.x;
    const int wid = tid >> 6, lane = tid & 63, quad = lane >> 4, ln = lane & 15;
    const int wm = wid >> 2, wn = wid & 3;   // 2x4 wave grid, wave tile 64x32
    const int t0 = blockIdx.x * 128, n0 = blockIdx.y * 128;

    // wave-uniform staging assignment: waves 0-3 -> A chunks, 4-7 -> B chunks
    const bool stA = (wid < 4);
    const u16* gbase = stA ? ctx : wo;
    const int r0 = stA ? t0 : n0;
    const int cbase = (wid & 3) * 4;         // 4 chunks of 1 KB per wave

    f32x4 acc[4][2];
#pragma unroll
    for (int im = 0; im < 4; im++)
#pragma unroll
        for (int in = 0; in < 2; in++) acc[im][in] = (f32x4){0.f, 0.f, 0.f, 0.f};

    // per-lane staging source geometry (swizzled global source, linear LDS)
    const int sb   = cbase * 1024 + lane * 16;
    const int srow = sb >> 7;
    const int scb  = (sb & 127) ^ ((srow & 7) << 4);

#define O_STAGE(buf, k0)                                                              \
    {                                                                                 \
        const u16* g = gbase + (long)(r0 + srow) * 1024 + (k0) + (scb >> 1);          \
        u16* d = (stA ? &As[buf][0] : &Bs[buf][0]) + cbase * 512;                     \
        _Pragma("unroll")                                                             \
        for (int i = 0; i < 4; i++) {                                                 \
            __builtin_amdgcn_global_load_lds(                                         \
                (const __attribute__((address_space(1))) void*)(g + (long)i * 8 * 1024), \
                (__attribute__((address_space(3))) void*)(d + i * 512), 16, 0, 0);    \
        }                                                                             \
    }

    O_STAGE(0, 0);
    __syncthreads();

    int cur = 0;
    for (int k0 = 0; k0 < 1024; k0 += 64) {
        if (k0 + 64 < 1024) O_STAGE(cur ^ 1, k0 + 64);
        const char* Ac = (const char*)&As[cur][0];
        const char* Bc = (const char*)&Bs[cur][0];
#pragma unroll
        for (int ks = 0; ks < 2; ks++) {
            bf16x8 af[4], bfr[2];
#pragma unroll
            for (int im = 0; im < 4; im++) {
                int r = wm * 64 + im * 16 + ln;
                int byt = (r * 128 + ks * 64 + quad * 16) ^ ((r & 7) << 4);
                af[im] = *reinterpret_cast<const bf16x8*>(Ac + byt);
            }
#pragma unroll
            for (int in = 0; in < 2; in++) {
                int r = wn * 32 + in * 16 + ln;
                int byt = (r * 128 + ks * 64 + quad * 16) ^ ((r & 7) << 4);
                bfr[in] = *reinterpret_cast<const bf16x8*>(Bc + byt);
            }
#pragma unroll
            for (int im = 0; im < 4; im++)
#pragma unroll
                for (int in = 0; in < 2; in++)
                    acc[im][in] = __builtin_amdgcn_mfma_f32_16x16x32_bf16(af[im], bfr[in], acc[im][in], 0, 0, 0);
        }
        // single barrier: (a) protects buf[cur] reuse, (b) drains DMA into buf^1
        __syncthreads();
        cur ^= 1;
    }
#undef O_STAGE

    const float s = so[0];
#pragma unroll
    for (int in = 0; in < 2; in++) {
        int col = n0 + wn * 32 + in * 16 + ln;
        float bias = bo[col];
#pragma unroll
        for (int im = 0; im < 4; im++) {
            int rbase = t0 + wm * 64 + im * 16 + quad * 4;
#pragma unroll
            for (int j2 = 0; j2 < 4; j2++)
                out[(long)(rbase + j2) * 1024 + col] = acc[im][in][j2] * s + bias;
        }
    }
}

// ---------------------------------------------------------------------------
extern "C" void kernel_launch(void* const* d_in, const int* in_sizes, int n_in,
                              void* d_out, int out_size, void* d_ws, size_t ws_size,
                              hipStream_t stream) {
    const float* x   = (const float*)d_in[0];
    const float* w_q = (const float*)d_in[1];
    const float* s_q = (const float*)d_in[2];
    const float* b_q = (const float*)d_in[3];
    const float* w_k = (const float*)d_in[4];
    const float* s_k = (const float*)d_in[5];
    const float* b_k = (const float*)d_in[6];
    const float* w_v = (const float*)d_in[7];
    const float* s_v = (const float*)d_in[8];
    const float* b_v = (const float*)d_in[9];
    const float* w_o = (const float*)d_in[10];
    const float* s_o = (const float*)d_in[11];
    const float* b_o = (const float*)d_in[12];

    if (ws_size < (size_t)50331648) return;  // need 48 MB of scratch

    u16* ws     = (u16*)d_ws;
    u16* x_bf   = ws;                    // 4096*1024
    u16* wq_bf  = x_bf  + 4194304;       // 1024*1024 each
    u16* wk_bf  = wq_bf + 1048576;
    u16* wv_bf  = wk_bf + 1048576;
    u16* wo_bf  = wv_bf + 1048576;
    u16* q_ws   = wo_bf + 1048576;       // [32 bh][2048 s][64 d]
    u16* k_ws   = q_ws  + 4194304;
    u16* v_ws   = k_ws  + 4194304;       // [32 bh][64 d][2048 s]
    u16* ctx_ws = v_ws  + 4194304;       // [4096 t][1024]

    convert_kernel<<<dim3(8192), dim3(256), 0, stream>>>(x, w_q, w_k, w_v, w_o, ws);
    qkv_gemm<<<dim3(32, 8, 3), dim3(512), 0, stream>>>(x_bf, wq_bf, wk_bf, wv_bf,
                                                       s_q, s_k, s_v, b_q, b_k, b_v,
                                                       q_ws, k_ws, v_ws);
    attn_kernel<<<dim3(16, 32), dim3(512), 0, stream>>>(q_ws, k_ws, v_ws, ctx_ws);
    o_gemm<<<dim3(32, 8), dim3(512), 0, stream>>>(ctx_ws, wo_bf, s_o, b_o, (float*)d_out);
}